// Round 5
// baseline (241.268 us; speedup 1.0000x reference)
//
#include <hip/hip_runtime.h>
#include <math.h>

#define Hh 12
#define S_LEN 2048
#define D_MODEL 768
#define HD 64

static constexpr float MAXLS = 4.6051701859880914f; // log(1/0.01)

typedef short bf16x8 __attribute__((ext_vector_type(8)));
typedef float f32x4  __attribute__((ext_vector_type(4)));
typedef float f32x16 __attribute__((ext_vector_type(16)));
typedef unsigned short u16x4 __attribute__((ext_vector_type(4)));
typedef unsigned short u16x8 __attribute__((ext_vector_type(8)));
typedef unsigned int u32x4 __attribute__((ext_vector_type(4)));

__device__ __forceinline__ unsigned short f2bf(float x) {
    unsigned int u = __builtin_bit_cast(unsigned int, x);
    unsigned int r = (u + 0x7FFF + ((u >> 16) & 1)) >> 16;
    return (unsigned short)r;
}

__device__ __forceinline__ unsigned int cvtpk(float a, float b) {
    unsigned int r;
    asm("v_cvt_pk_bf16_f32 %0, %1, %2" : "=v"(r) : "v"(a), "v"(b));
    return r;
}

__device__ __forceinline__ void gload16(const void* g, void* l) {
    __builtin_amdgcn_global_load_lds(
        (const __attribute__((address_space(1))) unsigned int*)g,
        (__attribute__((address_space(3))) unsigned int*)l, 16, 0, 0);
}

// ---------------- fp32 -> bf16 convert: hs, Wq|Wk|Wv (concat), Wo ----------------
__global__ __launch_bounds__(256)
void convert_bf16(const float* __restrict__ hs,
                  const float* __restrict__ Wq, const float* __restrict__ Wk,
                  const float* __restrict__ Wv, const float* __restrict__ Wo,
                  unsigned short* __restrict__ hsb,
                  unsigned short* __restrict__ wqkvb,
                  unsigned short* __restrict__ wob)
{
    const long long N0 = 8192LL * 768;
    const long long NW = 768LL * 768;
    const long long e  = ((long long)blockIdx.x * 256 + threadIdx.x) * 8;
    const float* src; unsigned short* dst;
    if (e < N0) { src = hs + e; dst = hsb + e; }
    else if (e < N0 + 3*NW) {
        const long long r = e - N0;
        const int z = (int)(r / NW);
        src = (z == 0 ? Wq : z == 1 ? Wk : Wv) + (r - (long long)z * NW);
        dst = wqkvb + r;
    } else {
        const long long r = e - N0 - 3*NW;
        src = Wo + r; dst = wob + r;
    }
    const float4 f0 = *(const float4*)src;
    const float4 f1 = *(const float4*)(src + 4);
    u16x8 o;
    o[0]=f2bf(f0.x); o[1]=f2bf(f0.y); o[2]=f2bf(f0.z); o[3]=f2bf(f0.w);
    o[4]=f2bf(f1.x); o[5]=f2bf(f1.y); o[6]=f2bf(f1.z); o[7]=f2bf(f1.w);
    *(u16x8*)dst = o;
}

// ---------------- bf16 MFMA GEMM: C = A @ W^T (+bias) ----------------
// MODE 0 (QKV, N=2304): z<2: fused L2-norm (+scale for q) -> bf16 [B,H,S,64].
//   z==2: bf16 V^T -> [B,H,64,S], kv bits 2<->3 swapped within each 64-block of s.
// MODE 1: fp32 out[m][768] + bias.
template<int MODE>
__global__ __launch_bounds__(256)
void gemm_bf16(const unsigned short* __restrict__ A,
               const unsigned short* __restrict__ Wt,
               const float* __restrict__ b0, const float* __restrict__ b1,
               const float* __restrict__ b2, const float* __restrict__ ls,
               unsigned short* __restrict__ qb, unsigned short* __restrict__ kb,
               unsigned short* __restrict__ vt, float* __restrict__ out)
{
    constexpr int K = 768;
    __shared__ char As[16384];
    __shared__ char Bs[16384];

    const int tid = threadIdx.x, w = tid >> 6, l = tid & 63;
    const int wr = w >> 1, wc = w & 1, hi = l >> 4, ll = l & 15;
    const int n0 = blockIdx.x * 128, m0 = blockIdx.y * 128;

    const int srow = l >> 3;
    const int sch  = (l & 7) ^ srow;
    const char* Ab = (const char*)(A  + (size_t)(m0 + w*32) * K) + srow * (K*2) + sch * 16;
    const char* Bb = (const char*)(Wt + (size_t)(n0 + w*32) * K) + srow * (K*2) + sch * 16;
    char* AsW = As + (w*32) * 128;
    char* BsW = Bs + (w*32) * 128;

    f32x4 acc[4][4];
    #pragma unroll
    for (int i = 0; i < 4; ++i)
        #pragma unroll
        for (int j = 0; j < 4; ++j) acc[i][j] = (f32x4){0.f,0.f,0.f,0.f};

    for (int kt = 0; kt < K/64; ++kt) {
        __syncthreads();
        #pragma unroll
        for (int s = 0; s < 4; ++s) {
            gload16(Ab + kt*128 + s*8*(K*2), AsW + s*1024);
            gload16(Bb + kt*128 + s*8*(K*2), BsW + s*1024);
        }
        __syncthreads();

        bf16x8 af[2][4], bf[2][4];
        #pragma unroll
        for (int kk = 0; kk < 2; ++kk) {
            const int pc = kk*4 + hi;
            #pragma unroll
            for (int i = 0; i < 4; ++i) {
                const int ra = wr*64 + i*16 + ll;
                af[kk][i] = *(const bf16x8*)(As + ra*128 + ((pc ^ (ra & 7)) << 4));
                const int rb = wc*64 + i*16 + ll;
                bf[kk][i] = *(const bf16x8*)(Bs + rb*128 + ((pc ^ (rb & 7)) << 4));
            }
        }
        #pragma unroll
        for (int kk = 0; kk < 2; ++kk)
            #pragma unroll
            for (int i = 0; i < 4; ++i)
                #pragma unroll
                for (int j = 0; j < 4; ++j)
                    acc[i][j] = __builtin_amdgcn_mfma_f32_16x16x32_bf16(af[kk][i], bf[kk][j], acc[i][j], 0, 0, 0);
    }

    if (MODE == 0) {
        const int z  = n0 / 768;
        const int nl = (n0 % 768) + wc*64;
        const int h  = nl >> 6;
        const int b  = m0 >> 11;
        const int s0 = (m0 & (S_LEN-1)) + wr*64;
        const float* bias = (z == 0) ? b0 : (z == 1) ? b1 : b2;
        float bj[4];
        #pragma unroll
        for (int j = 0; j < 4; ++j) bj[j] = bias[nl + j*16 + ll];

        if (z < 2) {
            const float sc = (z == 0) ? expf(fminf(ls[h], MAXLS)) : 1.0f;
            unsigned short* dst = (z == 0 ? qb : kb) + ((size_t)(b*Hh + h) * S_LEN) * HD;
            #pragma unroll
            for (int i = 0; i < 4; ++i) {
                #pragma unroll
                for (int r = 0; r < 4; ++r) {
                    float v[4]; float ss = 0.f;
                    #pragma unroll
                    for (int j = 0; j < 4; ++j) { v[j] = acc[i][j][r] + bj[j]; ss += v[j]*v[j]; }
                    #pragma unroll
                    for (int mm = 1; mm < 16; mm <<= 1) ss += __shfl_xor(ss, mm, 64);
                    const float inv = sc / fmaxf(sqrtf(ss), 1e-12f);
                    const int s = s0 + i*16 + hi*4 + r;
                    #pragma unroll
                    for (int j = 0; j < 4; ++j)
                        dst[(size_t)s * HD + j*16 + ll] = f2bf(v[j] * inv);
                }
            }
        } else {
            // V^T with kv-permutation: swap bits 2,3 of s within each 64-block
            const int hsw = ((hi & 1) << 1) | (hi >> 1);
            #pragma unroll
            for (int j = 0; j < 4; ++j) {
                const int d = (nl & 63) + j*16 + ll;
                #pragma unroll
                for (int i = 0; i < 4; ++i) {
                    const int s = s0 + i*16 + hsw*4;
                    u16x4 o;
                    #pragma unroll
                    for (int r = 0; r < 4; ++r) o[r] = f2bf(acc[i][j][r] + bj[j]);
                    *(u16x4*)(vt + ((size_t)(b*Hh + h) * HD + d) * S_LEN + s) = o;
                }
            }
        }
    } else {
        #pragma unroll
        for (int i = 0; i < 4; ++i)
            #pragma unroll
            for (int j = 0; j < 4; ++j) {
                const int n = n0 + wc*64 + j*16 + ll;
                const float bn = b0[n];
                #pragma unroll
                for (int r = 0; r < 4; ++r) {
                    const int m = m0 + wr*64 + i*16 + hi*4 + r;
                    out[(size_t)m * D_MODEL + n] = acc[i][j][r] + bn;
                }
            }
    }
}

// ---------------- Flash attention v3: chunk-major LDS + single-barrier dbuf ----------------
// Block: 4 waves x 32 q = 128 q rows. LDS: 2 bufs x (K 8KB + V 8KB) = 32KB.
// LDS layout per tile: [8 chunks][64 rows][16B] -> wave reads are two contiguous
// 512B runs (conflict-free), chunk offsets are compile-time immediates.
__global__ __launch_bounds__(256)
void attn_mfma3(const char* __restrict__ qb_, const char* __restrict__ kb_,
                const char* __restrict__ vtb_, const float* __restrict__ ls,
                unsigned short* __restrict__ ctx)
{
    __shared__ char smem[32768];

    const int flat = blockIdx.x;          // 0..767
    const int xcd = flat & 7, ix = flat >> 3;
    const int bh = xcd * 6 + (ix >> 4);   // 6 bh per XCD
    const int q0 = (ix & 15) * 128;
    const int b = bh / Hh, h = bh % Hh;

    const int tid = threadIdx.x, w = tid >> 6, l = tid & 63;
    const int lq = l & 31, g = l >> 5;

    const float c1 = 1.4426950408889634f;
    const float sc = __expf(fminf(ls[h], MAXLS));
    const float c0 = -sc * c1;

    const char* qg = qb_ + ((size_t)bh * S_LEN + q0 + w * 32) * 128;
    const char* kg = kb_ + (size_t)bh * S_LEN * 128 + (size_t)l * 128;   // lane = kv row
    const char* vg = vtb_ + (size_t)bh * HD * (S_LEN * 2) + (size_t)l * 4096; // lane = d row

    // Q B-frags: lane = col q (lq), k-elems d = s*16 + g*8 + j
    bf16x8 qf[4];
    #pragma unroll
    for (int s = 0; s < 4; ++s)
        qf[s] = *(const bf16x8*)(qg + lq * 128 + s * 32 + g * 16);

    f32x16 acco0, acco1;
    #pragma unroll
    for (int i = 0; i < 16; ++i) { acco0[i] = 0.f; acco1[i] = 0.f; }
    float lsum = 0.f;

    // staging: wave w stages chunks {w, w+4} of K and V into buf.
    // K chunk c: lane l -> global K[kt*64+l][c*16..+16), LDS dst + l*16.
    // V chunk c: lane l -> global vT[d=l][kt*128 + c*16..+16).
#define STAGE(buf, kt) do {                                                  \
        char* dstS = smem + ((buf) << 14);                                   \
        gload16(kg + (size_t)(kt) * 8192 + w * 16,        dstS + w * 1024);          \
        gload16(kg + (size_t)(kt) * 8192 + (w+4) * 16,    dstS + (w+4) * 1024);      \
        gload16(vg + (size_t)(kt) * 128 + w * 16,         dstS + 8192 + w * 1024);   \
        gload16(vg + (size_t)(kt) * 128 + (w+4) * 16,     dstS + 8192 + (w+4) * 1024); \
    } while (0)

    STAGE(0, 0);
    __syncthreads();
    int cur = 0;

    for (int kt = 0; kt < S_LEN / 64; ++kt) {
        if (kt < S_LEN / 64 - 1) STAGE(cur ^ 1, kt + 1);   // prefetch next tile

        const char* Ks = smem + (cur << 14);
        const char* Vs = Ks + 8192;

        // S^T = K . Q^T : rows kv, cols q (lane owns col q = lq)
        f32x16 sa0, sa1;
        #pragma unroll
        for (int i = 0; i < 16; ++i) { sa0[i] = 0.f; sa1[i] = 0.f; }

        __builtin_amdgcn_s_setprio(1);
        #pragma unroll
        for (int s = 0; s < 4; ++s) {
            const bf16x8 kf0 = *(const bf16x8*)(Ks + (2*s + g) * 1024 + lq * 16);
            sa0 = __builtin_amdgcn_mfma_f32_32x32x16_bf16(kf0, qf[s], sa0, 0, 0, 0);
            const bf16x8 kf1 = *(const bf16x8*)(Ks + (2*s + g) * 1024 + 512 + lq * 16);
            sa1 = __builtin_amdgcn_mfma_f32_32x32x16_bf16(kf1, qf[s], sa1, 0, 0, 0);
        }
        __builtin_amdgcn_s_setprio(0);

        // softmax (no max needed: s <= sc) + pack to bf16 pairs
        unsigned int pw[2][8];
        #pragma unroll
        for (int n = 0; n < 2; ++n) {
            const f32x16 sv = n ? sa1 : sa0;
            #pragma unroll
            for (int m = 0; m < 4; ++m) {
                const float p0 = __builtin_amdgcn_exp2f(fmaf(sv[4*m+0], c1, c0));
                const float p1 = __builtin_amdgcn_exp2f(fmaf(sv[4*m+1], c1, c0));
                const float p2 = __builtin_amdgcn_exp2f(fmaf(sv[4*m+2], c1, c0));
                const float p3 = __builtin_amdgcn_exp2f(fmaf(sv[4*m+3], c1, c0));
                lsum += (p0 + p1) + (p2 + p3);
                pw[n][2*m]   = cvtpk(p0, p1);
                pw[n][2*m+1] = cvtpk(p2, p3);
            }
        }

        // O^acc += P.V : A-frag = own p-words (kv order matches via V-permutation)
        __builtin_amdgcn_s_setprio(1);
        #pragma unroll
        for (int t = 0; t < 4; ++t) {
            u32x4 pu;
            pu[0] = pw[t>>1][4*(t&1)+0];
            pu[1] = pw[t>>1][4*(t&1)+1];
            pu[2] = pw[t>>1][4*(t&1)+2];
            pu[3] = pw[t>>1][4*(t&1)+3];
            const bf16x8 pa = __builtin_bit_cast(bf16x8, pu);
            const bf16x8 vf0 = *(const bf16x8*)(Vs + (2*t + g) * 1024 + lq * 16);
            acco0 = __builtin_amdgcn_mfma_f32_32x32x16_bf16(pa, vf0, acco0, 0, 0, 0);
            const bf16x8 vf1 = *(const bf16x8*)(Vs + (2*t + g) * 1024 + 512 + lq * 16);
            acco1 = __builtin_amdgcn_mfma_f32_32x32x16_bf16(pa, vf1, acco1, 0, 0, 0);
        }
        __builtin_amdgcn_s_setprio(0);

        __syncthreads();    // drains this iter's prefetch (vmcnt) + frees cur for restage
        cur ^= 1;
    }
#undef STAGE

    // epilogue: O[q][d] = acc / lsum ; ctx bf16 [B][S][768]
    lsum += __shfl_xor(lsum, 32, 64);
    #pragma unroll
    for (int r = 0; r < 16; ++r) {
        const int qrow = (r & 3) + 8 * (r >> 2) + 4 * g;
        const float inv = 1.0f / __shfl(lsum, (l & 32) | qrow, 64);
        unsigned short* crow = ctx + ((size_t)b * S_LEN + q0 + w * 32 + qrow) * D_MODEL + h * HD;
        crow[lq]      = f2bf(acco0[r] * inv);
        crow[32 + lq] = f2bf(acco1[r] * inv);
    }
}

extern "C" void kernel_launch(void* const* d_in, const int* in_sizes, int n_in,
                              void* d_out, int out_size, void* d_ws, size_t ws_size,
                              hipStream_t stream)
{
    const float* hs = (const float*)d_in[0];
    const float* Wq = (const float*)d_in[1];
    const float* bq = (const float*)d_in[2];
    const float* Wk = (const float*)d_in[3];
    const float* bk = (const float*)d_in[4];
    const float* Wv = (const float*)d_in[5];
    const float* bv = (const float*)d_in[6];
    const float* Wo = (const float*)d_in[7];
    const float* bo = (const float*)d_in[8];
    const float* ls = (const float*)d_in[9];
    float* out = (float*)d_out;

    const int B = 4;
    const size_t nHS = 8192ULL * 768;
    const size_t nW  = 768ULL * 768;
    const size_t nPB = (size_t)B * Hh * S_LEN * HD;

    unsigned short* hsb   = (unsigned short*)d_ws;
    unsigned short* wqkvb = hsb + nHS;
    unsigned short* wob   = wqkvb + 3 * nW;
    unsigned short* qbuf  = wob + nW;
    unsigned short* kbuf  = qbuf + nPB;
    unsigned short* vtb   = kbuf + nPB;
    unsigned short* cbuf  = vtb + nPB;

    hipLaunchKernelGGL(convert_bf16, dim3(4224), dim3(256), 0, stream,
                       hs, Wq, Wk, Wv, Wo, hsb, wqkvb, wob);

    hipLaunchKernelGGL((gemm_bf16<0>), dim3(2304/128, 8192/128), dim3(256), 0, stream,
                       hsb, wqkvb, bq, bk, bv, ls, qbuf, kbuf, vtb, nullptr);

    hipLaunchKernelGGL(attn_mfma3, dim3((S_LEN/128) * B * Hh), dim3(256), 0, stream,
                       (const char*)qbuf, (const char*)kbuf, (const char*)vtb, ls, cbuf);

    hipLaunchKernelGGL((gemm_bf16<1>), dim3(768/128, 8192/128), dim3(256), 0, stream,
                       cbuf, wob, bo, nullptr, nullptr, nullptr,
                       nullptr, nullptr, nullptr, out);
}

// Round 6
// 229.228 us; speedup vs baseline: 1.0525x; 1.0525x over previous
//
#include <hip/hip_runtime.h>
#include <math.h>

#define Hh 12
#define S_LEN 2048
#define D_MODEL 768
#define HD 64

static constexpr float MAXLS = 4.6051701859880914f; // log(1/0.01)
static constexpr float LOG2E = 1.4426950408889634f;

typedef short bf16x8 __attribute__((ext_vector_type(8)));
typedef float f32x4  __attribute__((ext_vector_type(4)));
typedef float f32x16 __attribute__((ext_vector_type(16)));
typedef unsigned short u16x4 __attribute__((ext_vector_type(4)));
typedef unsigned short u16x8 __attribute__((ext_vector_type(8)));
typedef unsigned int u32x4 __attribute__((ext_vector_type(4)));

__device__ __forceinline__ unsigned short f2bf(float x) {
    unsigned int u = __builtin_bit_cast(unsigned int, x);
    unsigned int r = (u + 0x7FFF + ((u >> 16) & 1)) >> 16;
    return (unsigned short)r;
}

__device__ __forceinline__ unsigned int cvtpk(float a, float b) {
    unsigned int r;
    asm("v_cvt_pk_bf16_f32 %0, %1, %2" : "=v"(r) : "v"(a), "v"(b));
    return r;
}

__device__ __forceinline__ void gload16(const void* g, void* l) {
    __builtin_amdgcn_global_load_lds(
        (const __attribute__((address_space(1))) unsigned int*)g,
        (__attribute__((address_space(3))) unsigned int*)l, 16, 0, 0);
}

// ---------------- fp32 -> bf16 convert: hs, Wq|Wk|Wv (concat), Wo ----------------
__global__ __launch_bounds__(256)
void convert_bf16(const float* __restrict__ hs,
                  const float* __restrict__ Wq, const float* __restrict__ Wk,
                  const float* __restrict__ Wv, const float* __restrict__ Wo,
                  unsigned short* __restrict__ hsb,
                  unsigned short* __restrict__ wqkvb,
                  unsigned short* __restrict__ wob)
{
    const long long N0 = 8192LL * 768;
    const long long NW = 768LL * 768;
    const long long e  = ((long long)blockIdx.x * 256 + threadIdx.x) * 8;
    const float* src; unsigned short* dst;
    if (e < N0) { src = hs + e; dst = hsb + e; }
    else if (e < N0 + 3*NW) {
        const long long r = e - N0;
        const int z = (int)(r / NW);
        src = (z == 0 ? Wq : z == 1 ? Wk : Wv) + (r - (long long)z * NW);
        dst = wqkvb + r;
    } else {
        const long long r = e - N0 - 3*NW;
        src = Wo + r; dst = wob + r;
    }
    const float4 f0 = *(const float4*)src;
    const float4 f1 = *(const float4*)(src + 4);
    u16x8 o;
    o[0]=f2bf(f0.x); o[1]=f2bf(f0.y); o[2]=f2bf(f0.z); o[3]=f2bf(f0.w);
    o[4]=f2bf(f1.x); o[5]=f2bf(f1.y); o[6]=f2bf(f1.z); o[7]=f2bf(f1.w);
    *(u16x8*)dst = o;
}

// ---------------- bf16 MFMA GEMM: C = A @ W^T (+bias) ----------------
// MODE 0 (QKV, N=2304):
//   z<2: fused L2-norm -> bf16 [B,H,S,64] in PERMUTED d-order d' = ll*4+j
//        (coalesced u16x4 stores; permutation identical for q,k so scores
//        are invariant). q additionally scaled by exp(min(ls,log100))*log2e.
//   z==2: bf16 V^T -> [B,H,64,S], kv bits 2<->3 swapped within each 64-block.
// MODE 1: fp32 out[m][768] + bias.
template<int MODE>
__global__ __launch_bounds__(256)
void gemm_bf16(const unsigned short* __restrict__ A,
               const unsigned short* __restrict__ Wt,
               const float* __restrict__ b0, const float* __restrict__ b1,
               const float* __restrict__ b2, const float* __restrict__ ls,
               unsigned short* __restrict__ qb, unsigned short* __restrict__ kb,
               unsigned short* __restrict__ vt, float* __restrict__ out)
{
    constexpr int K = 768;
    __shared__ char As[16384];
    __shared__ char Bs[16384];

    const int tid = threadIdx.x, w = tid >> 6, l = tid & 63;
    const int wr = w >> 1, wc = w & 1, hi = l >> 4, ll = l & 15;
    const int n0 = blockIdx.x * 128, m0 = blockIdx.y * 128;

    const int srow = l >> 3;
    const int sch  = (l & 7) ^ srow;
    const char* Ab = (const char*)(A  + (size_t)(m0 + w*32) * K) + srow * (K*2) + sch * 16;
    const char* Bb = (const char*)(Wt + (size_t)(n0 + w*32) * K) + srow * (K*2) + sch * 16;
    char* AsW = As + (w*32) * 128;
    char* BsW = Bs + (w*32) * 128;

    f32x4 acc[4][4];
    #pragma unroll
    for (int i = 0; i < 4; ++i)
        #pragma unroll
        for (int j = 0; j < 4; ++j) acc[i][j] = (f32x4){0.f,0.f,0.f,0.f};

    for (int kt = 0; kt < K/64; ++kt) {
        __syncthreads();
        #pragma unroll
        for (int s = 0; s < 4; ++s) {
            gload16(Ab + kt*128 + s*8*(K*2), AsW + s*1024);
            gload16(Bb + kt*128 + s*8*(K*2), BsW + s*1024);
        }
        __syncthreads();

        bf16x8 af[2][4], bf[2][4];
        #pragma unroll
        for (int kk = 0; kk < 2; ++kk) {
            const int pc = kk*4 + hi;
            #pragma unroll
            for (int i = 0; i < 4; ++i) {
                const int ra = wr*64 + i*16 + ll;
                af[kk][i] = *(const bf16x8*)(As + ra*128 + ((pc ^ (ra & 7)) << 4));
                const int rb = wc*64 + i*16 + ll;
                bf[kk][i] = *(const bf16x8*)(Bs + rb*128 + ((pc ^ (rb & 7)) << 4));
            }
        }
        #pragma unroll
        for (int kk = 0; kk < 2; ++kk)
            #pragma unroll
            for (int i = 0; i < 4; ++i)
                #pragma unroll
                for (int j = 0; j < 4; ++j)
                    acc[i][j] = __builtin_amdgcn_mfma_f32_16x16x32_bf16(af[kk][i], bf[kk][j], acc[i][j], 0, 0, 0);
    }

    if (MODE == 0) {
        const int z  = n0 / 768;
        const int nl = (n0 % 768) + wc*64;
        const int h  = nl >> 6;
        const int b  = m0 >> 11;
        const int s0 = (m0 & (S_LEN-1)) + wr*64;
        const float* bias = (z == 0) ? b0 : (z == 1) ? b1 : b2;
        float bj[4];
        #pragma unroll
        for (int j = 0; j < 4; ++j) bj[j] = bias[nl + j*16 + ll];

        if (z < 2) {
            // q carries exp(min(ls,log100)) * log2e so attention does p=exp2(s) raw
            const float sc = (z == 0) ? expf(fminf(ls[h], MAXLS)) * LOG2E : 1.0f;
            unsigned short* dst = (z == 0 ? qb : kb) + ((size_t)(b*Hh + h) * S_LEN) * HD;
            #pragma unroll
            for (int i = 0; i < 4; ++i) {
                float vv[4][4]; float ss[4] = {0.f, 0.f, 0.f, 0.f};
                #pragma unroll
                for (int r = 0; r < 4; ++r)
                    #pragma unroll
                    for (int j = 0; j < 4; ++j) {
                        const float x = acc[i][j][r] + bj[j];
                        vv[r][j] = x; ss[r] += x * x;
                    }
                #pragma unroll
                for (int mm = 1; mm < 16; mm <<= 1) {
                    ss[0] += __shfl_xor(ss[0], mm, 64);
                    ss[1] += __shfl_xor(ss[1], mm, 64);
                    ss[2] += __shfl_xor(ss[2], mm, 64);
                    ss[3] += __shfl_xor(ss[3], mm, 64);
                }
                #pragma unroll
                for (int r = 0; r < 4; ++r) {
                    const float inv = sc / fmaxf(sqrtf(ss[r]), 1e-12f);
                    const int s = s0 + i*16 + hi*4 + r;
                    u16x4 o;
                    #pragma unroll
                    for (int j = 0; j < 4; ++j) o[j] = f2bf(vv[r][j] * inv);
                    *(u16x4*)(dst + (size_t)s * HD + ll*4) = o;   // d' = ll*4+j
                }
            }
        } else {
            // V^T with kv-permutation: swap bits 2,3 of s within each 64-block
            const int hsw = ((hi & 1) << 1) | (hi >> 1);
            #pragma unroll
            for (int j = 0; j < 4; ++j) {
                const int d = (nl & 63) + j*16 + ll;
                #pragma unroll
                for (int i = 0; i < 4; ++i) {
                    const int s = s0 + i*16 + hsw*4;
                    u16x4 o;
                    #pragma unroll
                    for (int r = 0; r < 4; ++r) o[r] = f2bf(acc[i][j][r] + bj[j]);
                    *(u16x4*)(vt + ((size_t)(b*Hh + h) * HD + d) * S_LEN + s) = o;
                }
            }
        }
    } else {
        #pragma unroll
        for (int i = 0; i < 4; ++i)
            #pragma unroll
            for (int j = 0; j < 4; ++j) {
                const int n = n0 + wc*64 + j*16 + ll;
                const float bn = b0[n];
                #pragma unroll
                for (int r = 0; r < 4; ++r) {
                    const int m = m0 + wr*64 + i*16 + hi*4 + r;
                    out[(size_t)m * D_MODEL + n] = acc[i][j][r] + bn;
                }
            }
    }
}

// ---------------- Flash attention v4: no-offset exp2, lsum via MFMA ----------------
// Block: 4 waves x 32 q = 128 q rows. LDS: 2 bufs x (K 8KB + V 8KB) = 32KB.
// Chunk-major LDS [8 chunks][64 rows][16B] (conflict-free, immediate offsets).
// q pre-scaled by sc*log2e -> p = exp2(s) (softmax scale-invariance).
// Row sums accumulated on the MATRIX pipe: accl = mfma(pa, ones).
__global__ __launch_bounds__(256)
void attn_mfma4(const char* __restrict__ qb_, const char* __restrict__ kb_,
                const char* __restrict__ vtb_,
                unsigned short* __restrict__ ctx)
{
    __shared__ char smem[32768];

    const int flat = blockIdx.x;          // 0..767
    const int xcd = flat & 7, ix = flat >> 3;
    const int bh = xcd * 6 + (ix >> 4);   // 6 bh per XCD
    const int q0 = (ix & 15) * 128;
    const int b = bh / Hh, h = bh % Hh;

    const int tid = threadIdx.x, w = tid >> 6, l = tid & 63;
    const int lq = l & 31, g = l >> 5;

    const char* qg = qb_ + ((size_t)bh * S_LEN + q0 + w * 32) * 128;
    const char* kg = kb_ + (size_t)bh * S_LEN * 128 + (size_t)l * 128;       // lane = kv row
    const char* vg = vtb_ + (size_t)bh * HD * (S_LEN * 2) + (size_t)l * 4096; // lane = d row

    // Q B-frags: lane = col q (lq)
    bf16x8 qf[4];
    #pragma unroll
    for (int s = 0; s < 4; ++s)
        qf[s] = *(const bf16x8*)(qg + lq * 128 + s * 32 + g * 16);

    const short oneb = (short)0x3F80;   // bf16 1.0
    const bf16x8 onesf = {oneb, oneb, oneb, oneb, oneb, oneb, oneb, oneb};

    f32x16 acco0, acco1, accl;
    #pragma unroll
    for (int i = 0; i < 16; ++i) { acco0[i] = 0.f; acco1[i] = 0.f; accl[i] = 0.f; }

#define STAGE(buf, kt) do {                                                  \
        char* dstS = smem + ((buf) << 14);                                   \
        gload16(kg + (size_t)(kt) * 8192 + w * 16,        dstS + w * 1024);          \
        gload16(kg + (size_t)(kt) * 8192 + (w+4) * 16,    dstS + (w+4) * 1024);      \
        gload16(vg + (size_t)(kt) * 128 + w * 16,         dstS + 8192 + w * 1024);   \
        gload16(vg + (size_t)(kt) * 128 + (w+4) * 16,     dstS + 8192 + (w+4) * 1024); \
    } while (0)

    STAGE(0, 0);
    __syncthreads();
    int cur = 0;

    for (int kt = 0; kt < S_LEN / 64; ++kt) {
        if (kt < S_LEN / 64 - 1) STAGE(cur ^ 1, kt + 1);   // prefetch next tile

        const char* Ks = smem + (cur << 14);
        const char* Vs = Ks + 8192;

        // S^T = K . Q^T : rows kv, cols q (lane owns col q = lq)
        f32x16 sa0, sa1;
        #pragma unroll
        for (int i = 0; i < 16; ++i) { sa0[i] = 0.f; sa1[i] = 0.f; }

        __builtin_amdgcn_s_setprio(1);
        #pragma unroll
        for (int s = 0; s < 4; ++s) {
            const bf16x8 kf0 = *(const bf16x8*)(Ks + (2*s + g) * 1024 + lq * 16);
            sa0 = __builtin_amdgcn_mfma_f32_32x32x16_bf16(kf0, qf[s], sa0, 0, 0, 0);
            const bf16x8 kf1 = *(const bf16x8*)(Ks + (2*s + g) * 1024 + 512 + lq * 16);
            sa1 = __builtin_amdgcn_mfma_f32_32x32x16_bf16(kf1, qf[s], sa1, 0, 0, 0);
        }
        __builtin_amdgcn_s_setprio(0);

        // per kv-16-slice: 8 exp2 -> 4 cvtpk -> {PV0, PV1, lsum} MFMAs.
        // t's MFMAs overlap t+1's TRANS ops; lsum rides the matrix pipe.
        #pragma unroll
        for (int t = 0; t < 4; ++t) {
            float p[8];
            #pragma unroll
            for (int e = 0; e < 8; ++e) {
                const float sv = (t & 2) ? sa1[8*(t&1) + e] : sa0[8*(t&1) + e];
                p[e] = __builtin_amdgcn_exp2f(sv);    // no offset: scale cancels
            }
            u32x4 pu;
            pu[0] = cvtpk(p[0], p[1]);
            pu[1] = cvtpk(p[2], p[3]);
            pu[2] = cvtpk(p[4], p[5]);
            pu[3] = cvtpk(p[6], p[7]);
            const bf16x8 pa = __builtin_bit_cast(bf16x8, pu);

            __builtin_amdgcn_s_setprio(1);
            const bf16x8 vf0 = *(const bf16x8*)(Vs + (2*t + g) * 1024 + lq * 16);
            acco0 = __builtin_amdgcn_mfma_f32_32x32x16_bf16(pa, vf0, acco0, 0, 0, 0);
            const bf16x8 vf1 = *(const bf16x8*)(Vs + (2*t + g) * 1024 + 512 + lq * 16);
            acco1 = __builtin_amdgcn_mfma_f32_32x32x16_bf16(pa, vf1, acco1, 0, 0, 0);
            accl  = __builtin_amdgcn_mfma_f32_32x32x16_bf16(pa, onesf, accl, 0, 0, 0);
            __builtin_amdgcn_s_setprio(0);
        }

        __syncthreads();    // drains prefetch + frees cur for restage
        cur ^= 1;
    }
#undef STAGE

    // epilogue: O[q][d] = acco / accl ; lane's accl[r] IS lsum for its rows.
    #pragma unroll
    for (int r = 0; r < 16; ++r) {
        const int qrow = (r & 3) + 8 * (r >> 2) + 4 * g;
        const float inv = 1.0f / accl[r];
        unsigned short* crow = ctx + ((size_t)b * S_LEN + q0 + w * 32 + qrow) * D_MODEL + h * HD;
        crow[lq]      = f2bf(acco0[r] * inv);
        crow[32 + lq] = f2bf(acco1[r] * inv);
    }
}

extern "C" void kernel_launch(void* const* d_in, const int* in_sizes, int n_in,
                              void* d_out, int out_size, void* d_ws, size_t ws_size,
                              hipStream_t stream)
{
    const float* hs = (const float*)d_in[0];
    const float* Wq = (const float*)d_in[1];
    const float* bq = (const float*)d_in[2];
    const float* Wk = (const float*)d_in[3];
    const float* bk = (const float*)d_in[4];
    const float* Wv = (const float*)d_in[5];
    const float* bv = (const float*)d_in[6];
    const float* Wo = (const float*)d_in[7];
    const float* bo = (const float*)d_in[8];
    const float* ls = (const float*)d_in[9];
    float* out = (float*)d_out;

    const int B = 4;
    const size_t nHS = 8192ULL * 768;
    const size_t nW  = 768ULL * 768;
    const size_t nPB = (size_t)B * Hh * S_LEN * HD;

    unsigned short* hsb   = (unsigned short*)d_ws;
    unsigned short* wqkvb = hsb + nHS;
    unsigned short* wob   = wqkvb + 3 * nW;
    unsigned short* qbuf  = wob + nW;
    unsigned short* kbuf  = qbuf + nPB;
    unsigned short* vtb   = kbuf + nPB;
    unsigned short* cbuf  = vtb + nPB;

    hipLaunchKernelGGL(convert_bf16, dim3(4224), dim3(256), 0, stream,
                       hs, Wq, Wk, Wv, Wo, hsb, wqkvb, wob);

    hipLaunchKernelGGL((gemm_bf16<0>), dim3(2304/128, 8192/128), dim3(256), 0, stream,
                       hsb, wqkvb, bq, bk, bv, ls, qbuf, kbuf, vtb, nullptr);

    hipLaunchKernelGGL(attn_mfma4, dim3((S_LEN/128) * B * Hh), dim3(256), 0, stream,
                       (const char*)qbuf, (const char*)kbuf, (const char*)vtb, cbuf);

    hipLaunchKernelGGL((gemm_bf16<1>), dim3(768/128, 8192/128), dim3(256), 0, stream,
                       cbuf, wob, bo, nullptr, nullptr, nullptr,
                       nullptr, nullptr, nullptr, out);
}

// Round 7
// 214.844 us; speedup vs baseline: 1.1230x; 1.0670x over previous
//
#include <hip/hip_runtime.h>
#include <math.h>

#define Hh 12
#define S_LEN 2048
#define D_MODEL 768
#define HD 64

static constexpr float MAXLS = 4.6051701859880914f; // log(1/0.01)
static constexpr float LOG2E = 1.4426950408889634f;

typedef short bf16x8 __attribute__((ext_vector_type(8)));
typedef float f32x4  __attribute__((ext_vector_type(4)));
typedef float f32x16 __attribute__((ext_vector_type(16)));
typedef unsigned short u16x4 __attribute__((ext_vector_type(4)));
typedef unsigned short u16x8 __attribute__((ext_vector_type(8)));
typedef unsigned int u32x4 __attribute__((ext_vector_type(4)));

__device__ __forceinline__ unsigned short f2bf(float x) {
    unsigned int u = __builtin_bit_cast(unsigned int, x);
    unsigned int r = (u + 0x7FFF + ((u >> 16) & 1)) >> 16;
    return (unsigned short)r;
}

__device__ __forceinline__ unsigned int cvtpk(float a, float b) {
    unsigned int r;
    asm("v_cvt_pk_bf16_f32 %0, %1, %2" : "=v"(r) : "v"(a), "v"(b));
    return r;
}

__device__ __forceinline__ void gload16(const void* g, void* l) {
    __builtin_amdgcn_global_load_lds(
        (const __attribute__((address_space(1))) unsigned int*)g,
        (__attribute__((address_space(3))) unsigned int*)l, 16, 0, 0);
}

// ---------------- fp32 -> bf16 convert: hs, Wq|Wk|Wv (concat), Wo ----------------
__global__ __launch_bounds__(256)
void convert_bf16(const float* __restrict__ hs,
                  const float* __restrict__ Wq, const float* __restrict__ Wk,
                  const float* __restrict__ Wv, const float* __restrict__ Wo,
                  unsigned short* __restrict__ hsb,
                  unsigned short* __restrict__ wqkvb,
                  unsigned short* __restrict__ wob)
{
    const long long N0 = 8192LL * 768;
    const long long NW = 768LL * 768;
    const long long e  = ((long long)blockIdx.x * 256 + threadIdx.x) * 8;
    const float* src; unsigned short* dst;
    if (e < N0) { src = hs + e; dst = hsb + e; }
    else if (e < N0 + 3*NW) {
        const long long r = e - N0;
        const int z = (int)(r / NW);
        src = (z == 0 ? Wq : z == 1 ? Wk : Wv) + (r - (long long)z * NW);
        dst = wqkvb + r;
    } else {
        const long long r = e - N0 - 3*NW;
        src = Wo + r; dst = wob + r;
    }
    const float4 f0 = *(const float4*)src;
    const float4 f1 = *(const float4*)(src + 4);
    u16x8 o;
    o[0]=f2bf(f0.x); o[1]=f2bf(f0.y); o[2]=f2bf(f0.z); o[3]=f2bf(f0.w);
    o[4]=f2bf(f1.x); o[5]=f2bf(f1.y); o[6]=f2bf(f1.z); o[7]=f2bf(f1.w);
    *(u16x8*)dst = o;
}

// ---------------- bf16 MFMA GEMM: C = A @ W^T (+bias) ----------------
// MODE 0 (BN=128, QKV, N=2304):
//   z<2: fused L2-norm -> bf16 [B,H,S,64], permuted d' = ll*4+j; q scaled
//        by exp(min(ls,log100))*log2e.
//   z==2: bf16 V^T -> [B,H,64,S] via LDS transpose (coalesced stores), kv
//        bits 2<->3 swapped within each 64-block of s.
// MODE 1 (BN=64): fp32 out[m][768] + bias.
template<int MODE, int BN, int NWGX>
__global__ __launch_bounds__(256)
void gemm_bf16(const unsigned short* __restrict__ A,
               const unsigned short* __restrict__ Wt,
               const float* __restrict__ b0, const float* __restrict__ b1,
               const float* __restrict__ b2, const float* __restrict__ ls,
               unsigned short* __restrict__ qb, unsigned short* __restrict__ kb,
               unsigned short* __restrict__ vt, float* __restrict__ out)
{
    constexpr int K  = 768;
    constexpr int JW = BN / 32;            // B j-frags per wave
    __shared__ char As[16384];
    __shared__ char Bs[BN * 128];

    // bijective XCD-chunked swizzle (grid = NWGX*64, multiple of 8)
    constexpr int CPX = (NWGX * 64) / 8;
    const int bid = blockIdx.x;
    const int wg  = (bid & 7) * CPX + (bid >> 3);
    const int n0  = (wg % NWGX) * BN;
    const int m0  = (wg / NWGX) * 128;

    const int tid = threadIdx.x, w = tid >> 6, l = tid & 63;
    const int wr = w >> 1, wc = w & 1, hi = l >> 4, ll = l & 15;

    const int srow = l >> 3;
    const int sch  = (l & 7) ^ srow;
    const char* Ab = (const char*)(A  + (size_t)(m0 + w*32) * K) + srow * (K*2) + sch * 16;
    const char* Bb = (const char*)(Wt + (size_t)(n0 + w*(BN/4)) * K) + srow * (K*2) + sch * 16;
    char* AsW = As + (w*32) * 128;
    char* BsW = Bs + (w*(BN/4)) * 128;

    f32x4 acc[4][JW];
    #pragma unroll
    for (int i = 0; i < 4; ++i)
        #pragma unroll
        for (int j = 0; j < JW; ++j) acc[i][j] = (f32x4){0.f,0.f,0.f,0.f};

    for (int kt = 0; kt < K/64; ++kt) {
        __syncthreads();
        #pragma unroll
        for (int s = 0; s < 4; ++s)
            gload16(Ab + kt*128 + s*8*(K*2), AsW + s*1024);
        #pragma unroll
        for (int s = 0; s < JW; ++s)
            gload16(Bb + kt*128 + s*8*(K*2), BsW + s*1024);
        __syncthreads();

        bf16x8 af[2][4], bf[2][JW];
        #pragma unroll
        for (int kk = 0; kk < 2; ++kk) {
            const int pc = kk*4 + hi;
            #pragma unroll
            for (int i = 0; i < 4; ++i) {
                const int ra = wr*64 + i*16 + ll;
                af[kk][i] = *(const bf16x8*)(As + ra*128 + ((pc ^ (ra & 7)) << 4));
            }
            #pragma unroll
            for (int j = 0; j < JW; ++j) {
                const int rb = wc*(BN/2) + j*16 + ll;
                bf[kk][j] = *(const bf16x8*)(Bs + rb*128 + ((pc ^ (rb & 7)) << 4));
            }
        }
        #pragma unroll
        for (int kk = 0; kk < 2; ++kk)
            #pragma unroll
            for (int i = 0; i < 4; ++i)
                #pragma unroll
                for (int j = 0; j < JW; ++j)
                    acc[i][j] = __builtin_amdgcn_mfma_f32_16x16x32_bf16(af[kk][i], bf[kk][j], acc[i][j], 0, 0, 0);
    }

    if (MODE == 0) {
        const int z  = n0 / 768;
        const int nl = (n0 % 768) + wc*64;
        const int h  = nl >> 6;
        const int b  = m0 >> 11;
        const int s0 = (m0 & (S_LEN-1)) + wr*64;
        const float* bias = (z == 0) ? b0 : (z == 1) ? b1 : b2;
        float bj[4];
        #pragma unroll
        for (int j = 0; j < 4; ++j) bj[j] = bias[nl + j*16 + ll];

        if (z < 2) {
            const float sc = (z == 0) ? expf(fminf(ls[h], MAXLS)) * LOG2E : 1.0f;
            unsigned short* dst = (z == 0 ? qb : kb) + ((size_t)(b*Hh + h) * S_LEN) * HD;
            #pragma unroll
            for (int i = 0; i < 4; ++i) {
                float vv[4][4]; float ss[4] = {0.f, 0.f, 0.f, 0.f};
                #pragma unroll
                for (int r = 0; r < 4; ++r)
                    #pragma unroll
                    for (int j = 0; j < 4; ++j) {
                        const float x = acc[i][j][r] + bj[j];
                        vv[r][j] = x; ss[r] += x * x;
                    }
                #pragma unroll
                for (int mm = 1; mm < 16; mm <<= 1) {
                    ss[0] += __shfl_xor(ss[0], mm, 64);
                    ss[1] += __shfl_xor(ss[1], mm, 64);
                    ss[2] += __shfl_xor(ss[2], mm, 64);
                    ss[3] += __shfl_xor(ss[3], mm, 64);
                }
                #pragma unroll
                for (int r = 0; r < 4; ++r) {
                    const float inv = sc / fmaxf(sqrtf(ss[r]), 1e-12f);
                    const int s = s0 + i*16 + hi*4 + r;
                    u16x4 o;
                    #pragma unroll
                    for (int j = 0; j < 4; ++j) o[j] = f2bf(vv[r][j] * inv);
                    *(u16x4*)(dst + (size_t)s * HD + ll*4) = o;   // d' = ll*4+j
                }
            }
        } else {
            // V^T via LDS transpose. kv-permutation (swap s bits 2,3) folded
            // into the LDS write position; reads/stores fully linear.
            __syncthreads();   // all waves done with As/Bs K-loop reads (z uniform per block)
            char* T = (w < 2 ? As : Bs) + (w & 1) * 8192;   // [64 d][64 s] bf16, chunk-XOR swz
            const int ch_add = hi & 1;     // (hsw>>1)
            const int half8  = hi >> 1;    // (hsw&1)*8 bytes
            #pragma unroll
            for (int j = 0; j < 4; ++j) {
                const int d = j*16 + ll;
                #pragma unroll
                for (int i = 0; i < 4; ++i) {
                    u16x4 o;
                    #pragma unroll
                    for (int r = 0; r < 4; ++r) o[r] = f2bf(acc[i][j][r] + bj[j]);
                    const int byteoff = d*128 + (((i*2 + ch_add) ^ (d & 7)) << 4) + half8*8;
                    *(u16x4*)(T + byteoff) = o;
                }
            }
            // wave-local readback (compiler inserts lgkmcnt) -> coalesced stores
            const int dl = l >> 2;
            #pragma unroll
            for (int dp = 0; dp < 4; ++dp) {
                const int d = dp*16 + dl;
                unsigned short* vrow = vt + ((size_t)(b*Hh + h) * HD + d) * S_LEN + s0;
                #pragma unroll
                for (int rep = 0; rep < 2; ++rep) {
                    const int c = (l & 3) + rep*4;
                    const u16x8 vv = *(const u16x8*)(T + d*128 + ((c ^ (d & 7)) << 4));
                    *(u16x8*)(vrow + c*8) = vv;
                }
            }
        }
    } else {
        #pragma unroll
        for (int i = 0; i < 4; ++i)
            #pragma unroll
            for (int j = 0; j < JW; ++j) {
                const int n = n0 + wc*(BN/2) + j*16 + ll;
                const float bn = b0[n];
                #pragma unroll
                for (int r = 0; r < 4; ++r) {
                    const int m = m0 + wr*64 + i*16 + hi*4 + r;
                    out[(size_t)m * D_MODEL + n] = acc[i][j][r] + bn;
                }
            }
    }
}

// ---------------- Flash attention v5: 2-tile pipeline (QK(t+1) || softmax+PV(t)) ----
// Triple-buffered LDS (3 x 16KB). q pre-scaled by sc*log2e -> p = exp2(s).
// lsum via MFMA(pa, ones). Chunk-major conflict-free LDS layout.
__global__ __launch_bounds__(256, 4)
void attn_mfma5(const char* __restrict__ qb_, const char* __restrict__ kb_,
                const char* __restrict__ vtb_,
                unsigned short* __restrict__ ctx)
{
    __shared__ char smem[49152];
    constexpr int NT = S_LEN / 64;

    const int flat = blockIdx.x;          // 0..767
    const int xcd = flat & 7, ix = flat >> 3;
    const int bh = xcd * 6 + (ix >> 4);   // 6 bh per XCD
    const int q0 = (ix & 15) * 128;
    const int b = bh / Hh, h = bh % Hh;

    const int tid = threadIdx.x, w = tid >> 6, l = tid & 63;
    const int lq = l & 31, g = l >> 5;

    const char* qg = qb_ + ((size_t)bh * S_LEN + q0 + w * 32) * 128;
    const char* kg = kb_ + (size_t)bh * S_LEN * 128 + (size_t)l * 128;        // lane = kv row
    const char* vg = vtb_ + (size_t)bh * HD * (S_LEN * 2) + (size_t)l * 4096; // lane = d row

    bf16x8 qf[4];
    #pragma unroll
    for (int s = 0; s < 4; ++s)
        qf[s] = *(const bf16x8*)(qg + lq * 128 + s * 32 + g * 16);

    const short oneb = (short)0x3F80;
    const bf16x8 onesf = {oneb, oneb, oneb, oneb, oneb, oneb, oneb, oneb};

    f32x16 acco0, acco1, accl;
    #pragma unroll
    for (int i = 0; i < 16; ++i) { acco0[i] = 0.f; acco1[i] = 0.f; accl[i] = 0.f; }

#define STAGE(bi, kt) do {                                                   \
        char* dstS = smem + ((bi) << 14);                                    \
        gload16(kg + (size_t)(kt) * 8192 + w * 16,        dstS + w * 1024);          \
        gload16(kg + (size_t)(kt) * 8192 + (w+4) * 16,    dstS + (w+4) * 1024);      \
        gload16(vg + (size_t)(kt) * 128 + w * 16,         dstS + 8192 + w * 1024);   \
        gload16(vg + (size_t)(kt) * 128 + (w+4) * 16,     dstS + 8192 + (w+4) * 1024); \
    } while (0)

    // QK^T for one tile: S^T rows kv, cols q (lane owns q-col lq)
    auto qk = [&](const char* Ks, f32x16& o0, f32x16& o1) {
        __builtin_amdgcn_s_setprio(1);
        #pragma unroll
        for (int s = 0; s < 4; ++s) {
            const bf16x8 kf0 = *(const bf16x8*)(Ks + (2*s + g) * 1024 + lq * 16);
            o0 = __builtin_amdgcn_mfma_f32_32x32x16_bf16(kf0, qf[s], o0, 0, 0, 0);
            const bf16x8 kf1 = *(const bf16x8*)(Ks + (2*s + g) * 1024 + 512 + lq * 16);
            o1 = __builtin_amdgcn_mfma_f32_32x32x16_bf16(kf1, qf[s], o1, 0, 0, 0);
        }
        __builtin_amdgcn_s_setprio(0);
    };

    // softmax + PV + lsum for one tile
    auto softmax_pv = [&](const f32x16& s0v, const f32x16& s1v, const char* Vs) {
        #pragma unroll
        for (int t = 0; t < 4; ++t) {
            float p[8];
            #pragma unroll
            for (int e = 0; e < 8; ++e) {
                const float sv = (t & 2) ? s1v[8*(t&1) + e] : s0v[8*(t&1) + e];
                p[e] = __builtin_amdgcn_exp2f(sv);
            }
            u32x4 pu;
            pu[0] = cvtpk(p[0], p[1]);
            pu[1] = cvtpk(p[2], p[3]);
            pu[2] = cvtpk(p[4], p[5]);
            pu[3] = cvtpk(p[6], p[7]);
            const bf16x8 pa = __builtin_bit_cast(bf16x8, pu);

            __builtin_amdgcn_s_setprio(1);
            const bf16x8 vf0 = *(const bf16x8*)(Vs + (2*t + g) * 1024 + lq * 16);
            acco0 = __builtin_amdgcn_mfma_f32_32x32x16_bf16(pa, vf0, acco0, 0, 0, 0);
            const bf16x8 vf1 = *(const bf16x8*)(Vs + (2*t + g) * 1024 + 512 + lq * 16);
            acco1 = __builtin_amdgcn_mfma_f32_32x32x16_bf16(pa, vf1, acco1, 0, 0, 0);
            accl  = __builtin_amdgcn_mfma_f32_32x32x16_bf16(pa, onesf, accl, 0, 0, 0);
            __builtin_amdgcn_s_setprio(0);
        }
    };

    // prologue: tiles 0 and 1 staged; sa for tile 0 computed
    STAGE(0, 0);
    __syncthreads();
    STAGE(1, 1);
    f32x16 sa0c, sa1c;
    #pragma unroll
    for (int i = 0; i < 16; ++i) { sa0c[i] = 0.f; sa1c[i] = 0.f; }
    qk(smem, sa0c, sa1c);
    __syncthreads();           // buf1 staged & drained

    int bc = 0, bn = 1, bs = 2;
    #pragma unroll 3
    for (int kt = 0; kt < NT - 1; ++kt) {
        if (kt + 2 < NT) STAGE(bs, kt + 2);
        // QK of tile kt+1 (independent MFMAs) overlaps softmax of tile kt
        f32x16 sa0n, sa1n;
        #pragma unroll
        for (int i = 0; i < 16; ++i) { sa0n[i] = 0.f; sa1n[i] = 0.f; }
        qk(smem + (bn << 14), sa0n, sa1n);
        softmax_pv(sa0c, sa1c, smem + (bc << 14) + 8192);
        __syncthreads();       // frees buf bc; drains STAGE(kt+2)
        sa0c = sa0n; sa1c = sa1n;
        const int t0 = bc; bc = bn; bn = bs; bs = t0;
    }
    // tail tile NT-1
    softmax_pv(sa0c, sa1c, smem + (bc << 14) + 8192);
#undef STAGE

    // epilogue: O[q][d] = acco / accl
    #pragma unroll
    for (int r = 0; r < 16; ++r) {
        const int qrow = (r & 3) + 8 * (r >> 2) + 4 * g;
        const float inv = 1.0f / accl[r];
        unsigned short* crow = ctx + ((size_t)b * S_LEN + q0 + w * 32 + qrow) * D_MODEL + h * HD;
        crow[lq]      = f2bf(acco0[r] * inv);
        crow[32 + lq] = f2bf(acco1[r] * inv);
    }
}

extern "C" void kernel_launch(void* const* d_in, const int* in_sizes, int n_in,
                              void* d_out, int out_size, void* d_ws, size_t ws_size,
                              hipStream_t stream)
{
    const float* hs = (const float*)d_in[0];
    const float* Wq = (const float*)d_in[1];
    const float* bq = (const float*)d_in[2];
    const float* Wk = (const float*)d_in[3];
    const float* bk = (const float*)d_in[4];
    const float* Wv = (const float*)d_in[5];
    const float* bv = (const float*)d_in[6];
    const float* Wo = (const float*)d_in[7];
    const float* bo = (const float*)d_in[8];
    const float* ls = (const float*)d_in[9];
    float* out = (float*)d_out;

    const int B = 4;
    const size_t nHS = 8192ULL * 768;
    const size_t nW  = 768ULL * 768;
    const size_t nPB = (size_t)B * Hh * S_LEN * HD;

    unsigned short* hsb   = (unsigned short*)d_ws;
    unsigned short* wqkvb = hsb + nHS;
    unsigned short* wob   = wqkvb + 3 * nW;
    unsigned short* qbuf  = wob + nW;
    unsigned short* kbuf  = qbuf + nPB;
    unsigned short* vtb   = kbuf + nPB;
    unsigned short* cbuf  = vtb + nPB;

    hipLaunchKernelGGL(convert_bf16, dim3(4224), dim3(256), 0, stream,
                       hs, Wq, Wk, Wv, Wo, hsb, wqkvb, wob);

    hipLaunchKernelGGL((gemm_bf16<0, 128, 18>), dim3(18 * 64), dim3(256), 0, stream,
                       hsb, wqkvb, bq, bk, bv, ls, qbuf, kbuf, vtb, nullptr);

    hipLaunchKernelGGL(attn_mfma5, dim3((S_LEN/128) * B * Hh), dim3(256), 0, stream,
                       (const char*)qbuf, (const char*)kbuf, (const char*)vtb, cbuf);

    hipLaunchKernelGGL((gemm_bf16<1, 64, 12>), dim3(12 * 64), dim3(256), 0, stream,
                       cbuf, wob, bo, nullptr, nullptr, nullptr,
                       nullptr, nullptr, nullptr, out);
}